// Round 7
// baseline (397.565 us; speedup 1.0000x reference)
//
#include <hip/hip_runtime.h>
#include <hip/hip_bf16.h>

// CustomMHA (B=2,S=2048,D=1024,H=16,dh=64) for MI355X / gfx950.
//
//  1) cvt_split:  x, W_qkv f32 -> (hi,lo) bf16 pairs; W_o -> bf16.
//  2) gemm_qkv :  T = X @ Wqkv^T, split-bf16 (3 MFMA); pure-V col tiles plain.
//     2-PHASE double-buffered LDS staging with counted vmcnt (prefetch tile
//     t+1 across the barrier; never drain vmcnt to 0 mid-loop).
//     Epilogue scatters Q(hi,lo)[pre-scaled 1/32], K(hi,lo), V transposed.
//  3) attn      :  QBLK=16, 4096 one-wave blocks (4 waves/SIMD), longest-first.
//     Causal flash attn in s2 space; 3-MFMA split QK^T; denom via MFMA(P,1);
//     defer-max; P handoff fenced with lgkmcnt(0) only.
//  4) gemm_out :  Y = Yp @ Wo^T, 64x128 tiles (512 blocks, 2/CU), f32 out.

using bf16 = __hip_bfloat16;
typedef __attribute__((ext_vector_type(8))) short bf16x8v;   // 8 bf16 in 4 VGPRs
typedef __attribute__((ext_vector_type(4))) float f32x4;

#define MFMA_BF16(A, B, C) __builtin_amdgcn_mfma_f32_16x16x32_bf16((A), (B), (C), 0, 0, 0)

#define GLD_LDS16(g, l)                                                        \
  __builtin_amdgcn_global_load_lds(                                            \
      (const __attribute__((address_space(1))) void*)(g),                      \
      (__attribute__((address_space(3))) void*)(l), 16, 0, 0)

static __device__ __forceinline__ unsigned short bf_bits(float f) {
  bf16 b = __float2bfloat16(f);
  return *reinterpret_cast<unsigned short*>(&b);
}

// ---------------------------------------------------------------- converts --
__global__ __launch_bounds__(256) void cvt_split(const float* __restrict__ in,
                                                 bf16* __restrict__ hi,
                                                 bf16* __restrict__ lo, int n) {
  int i = (blockIdx.x * 256 + threadIdx.x) * 4;
  if (i >= n) return;
  const float4 v = *(const float4*)(in + i);
  float vv[4] = {v.x, v.y, v.z, v.w};
  ushort4 hb, lb;
  unsigned short* hp = &hb.x;
  unsigned short* lp = &lb.x;
#pragma unroll
  for (int j = 0; j < 4; ++j) {
    bf16 h = __float2bfloat16(vv[j]);
    float r = vv[j] - __bfloat162float(h);   // exact residual
    hp[j] = bf_bits(vv[j]);
    lp[j] = bf_bits(r);
  }
  *(ushort4*)(hi + i) = hb;
  *(ushort4*)(lo + i) = lb;
}

__global__ __launch_bounds__(256) void cvt_plain(const float* __restrict__ in,
                                                 bf16* __restrict__ out, int n) {
  int i = (blockIdx.x * 256 + threadIdx.x) * 4;
  if (i >= n) return;
  const float4 v = *(const float4*)(in + i);
  ushort4 ob;
  ob.x = bf_bits(v.x); ob.y = bf_bits(v.y); ob.z = bf_bits(v.z); ob.w = bf_bits(v.w);
  *(ushort4*)(out + i) = ob;
}

// ----------------------------------------------------------------- gemm_qkv --
// 128x128 tile, 256 thr (4 waves 2x2), BK=32, 2-phase dbuf staging.
__global__ __launch_bounds__(256) void gemm_qkv(
    const bf16* __restrict__ Ah, const bf16* __restrict__ Al,
    const bf16* __restrict__ Bh, const bf16* __restrict__ Bl,
    bf16* __restrict__ Qhi, bf16* __restrict__ Qlo,
    bf16* __restrict__ Khi, bf16* __restrict__ Klo,
    bf16* __restrict__ Vt) {
  const int K = 1024;
  const int NT = 24;  // 3072/128
  __shared__ __attribute__((aligned(16))) bf16 AsH[2][4096], AsL[2][4096],
                                               BsH[2][4096], BsL[2][4096];
  const int t = threadIdx.x;
  const int lane = t & 63;
  const int wave = t >> 6;
  const int wr = wave >> 1, wc = wave & 1;
  int bid = blockIdx.x;
  bid = (bid & 7) * (768 >> 3) + (bid >> 3);   // bijective XCD swizzle
  const int bm = bid / NT, bn = bid % NT;
  const int brow = bm * 128, bcol = bn * 128;
  const bool isV = (bcol >= 2048);
  const bf16* pAh = Ah + (size_t)brow * K;
  const bf16* pAl = Al + (size_t)brow * K;
  const bf16* pBh = Bh + (size_t)bcol * K;
  const bf16* pBl = Bl + (size_t)bcol * K;
  const int r0 = t >> 2;
  const int c0 = (t & 3) * 8;
  f32x4 acc[4][4] = {};

#define STAGE(buf, k0_)                                                        \
  {                                                                            \
    const int _k = (k0_);                                                      \
    GLD_LDS16(pAh + (size_t)r0 * K + _k + c0,        &AsH[buf][t * 8]);        \
    GLD_LDS16(pAh + (size_t)(r0 + 64) * K + _k + c0, &AsH[buf][2048 + t * 8]); \
    GLD_LDS16(pBh + (size_t)r0 * K + _k + c0,        &BsH[buf][t * 8]);        \
    GLD_LDS16(pBh + (size_t)(r0 + 64) * K + _k + c0, &BsH[buf][2048 + t * 8]); \
    if (!isV) {                                                                \
      GLD_LDS16(pAl + (size_t)r0 * K + _k + c0,        &AsL[buf][t * 8]);      \
      GLD_LDS16(pAl + (size_t)(r0 + 64) * K + _k + c0, &AsL[buf][2048 + t * 8]);\
      GLD_LDS16(pBl + (size_t)r0 * K + _k + c0,        &BsL[buf][t * 8]);      \
      GLD_LDS16(pBl + (size_t)(r0 + 64) * K + _k + c0, &BsL[buf][2048 + t * 8]);\
    }                                                                          \
  }

  STAGE(0, 0);                       // prologue: tile 0 into buf 0
  const int ao = (wr * 64 + (lane & 15)) * 32 + (lane >> 4) * 8;
  const int bo = (wc * 64 + (lane & 15)) * 32 + (lane >> 4) * 8;
  for (int tk = 0; tk < 32; ++tk) {
    const int cur = tk & 1;
    if (tk < 31) {
      STAGE(cur ^ 1, (tk + 1) * 32);       // prefetch next tile
      // wait for CURRENT tile's loads only; leave the prefetch in flight.
      if (!isV) asm volatile("s_waitcnt vmcnt(8)" ::: "memory");
      else      asm volatile("s_waitcnt vmcnt(4)" ::: "memory");
    } else {
      asm volatile("s_waitcnt vmcnt(0)" ::: "memory");
    }
    __builtin_amdgcn_sched_barrier(0);
    __builtin_amdgcn_s_barrier();          // all waves' cur-tile staging done
    asm volatile("" ::: "memory");
    bf16x8v ah[4], bh_[4];
#pragma unroll
    for (int i = 0; i < 4; ++i) {
      ah[i]  = *(const bf16x8v*)&AsH[cur][ao + i * 512];
      bh_[i] = *(const bf16x8v*)&BsH[cur][bo + i * 512];
    }
    if (!isV) {
      bf16x8v al[4], bl_[4];
#pragma unroll
      for (int i = 0; i < 4; ++i) {
        al[i]  = *(const bf16x8v*)&AsL[cur][ao + i * 512];
        bl_[i] = *(const bf16x8v*)&BsL[cur][bo + i * 512];
      }
#pragma unroll
      for (int i = 0; i < 4; ++i)
#pragma unroll
        for (int j = 0; j < 4; ++j) {
          acc[i][j] = MFMA_BF16(ah[i], bh_[j], acc[i][j]);
          acc[i][j] = MFMA_BF16(ah[i], bl_[j], acc[i][j]);
          acc[i][j] = MFMA_BF16(al[i], bh_[j], acc[i][j]);
        }
    } else {
#pragma unroll
      for (int i = 0; i < 4; ++i)
#pragma unroll
        for (int j = 0; j < 4; ++j)
          acc[i][j] = MFMA_BF16(ah[i], bh_[j], acc[i][j]);
    }
    asm volatile("" ::: "memory");
    __builtin_amdgcn_sched_barrier(0);
    __builtin_amdgcn_s_barrier();          // reads of cur done -> may overwrite
    asm volatile("" ::: "memory");
  }
#undef STAGE
  // epilogue: split + scatter (V transposed); Q pre-scaled by 1/32.
#pragma unroll
  for (int i = 0; i < 4; ++i)
#pragma unroll
    for (int j = 0; j < 4; ++j)
#pragma unroll
      for (int e = 0; e < 4; ++e) {
        const int m = brow + wr * 64 + i * 16 + ((lane >> 4) << 2) + e;
        const int n = bcol + wc * 64 + j * 16 + (lane & 15);
        float v = acc[i][j][e];
        const int b = m >> 11, s = m & 2047;
        const int c = n >> 10, d = n & 1023;
        const int bh_i = (b << 4) | (s >> 7);
        const int s2 = ((s & 127) << 4) | (d >> 6);
        const int dh = d & 63;
        if (c == 2) {
          Vt[((size_t)bh_i << 17) | ((size_t)dh << 11) | (size_t)s2] = __float2bfloat16(v);
        } else {
          if (c == 0) v *= 0.03125f;
          const size_t idx = ((size_t)bh_i << 17) | ((size_t)s2 << 6) | (size_t)dh;
          bf16 hv = __float2bfloat16(v);
          bf16 lv = __float2bfloat16(v - __bfloat162float(hv));
          if (c == 0) { Qhi[idx] = hv; Qlo[idx] = lv; }
          else        { Khi[idx] = hv; Klo[idx] = lv; }
        }
      }
}

// --------------------------------------------------------------------- attn --
// QBLK=16: 1 wave / block, 4096 blocks (16/CU -> 4 waves/SIMD), longest-first.
// K/V loaded at use (TLP hides latency); P handoff fenced lgkmcnt(0)-only.
__global__ __launch_bounds__(64, 4) void attn_kernel(
    const bf16* __restrict__ Qhi, const bf16* __restrict__ Qlo,
    const bf16* __restrict__ Khi, const bf16* __restrict__ Klo,
    const bf16* __restrict__ Vt, bf16* __restrict__ Yp) {
  const int lane = threadIdx.x & 63;
  const int bh = blockIdx.x & 31;           // bh minor (bh%8 pins the XCD)
  const int c  = 127 - (blockIdx.x >> 5);   // 16-row chunk, longest first
  const int b = bh >> 4, h = bh & 15;
  const size_t base = (size_t)bh << 17;
  const bf16* qh_p = Qhi + base;
  const bf16* ql_p = Qlo + base;
  const bf16* kh_p = Khi + base;
  const bf16* kl_p = Klo + base;
  const bf16* v_p  = Vt + base;             // (dh, s2) layout
  const int qbase = c << 4;
  const int l15 = lane & 15;
  const int lg  = lane >> 4;
  __shared__ __attribute__((aligned(16))) bf16 Plds[16][72];

  bf16x8v qfh[2], qfl[2];
#pragma unroll
  for (int x2 = 0; x2 < 2; ++x2) {
    const size_t o = (size_t)(qbase + l15) * 64 + x2 * 32 + lg * 8;
    qfh[x2] = *(const bf16x8v*)(qh_p + o);
    qfl[x2] = *(const bf16x8v*)(ql_p + o);
  }
  bf16x8v ones8;
#pragma unroll
  for (int j = 0; j < 8; ++j) ones8[j] = (short)0x3F80;  // bf16 1.0

  f32x4 oac[4] = {};
  f32x4 oden = {};
  float mrun = -3.0e38f;
  const float L2E = 1.4426950408889634f;
  const int nfull = c >> 2;                 // diagonal tile index

  for (int kt = 0; kt <= nfull; ++kt) {
    const int kb = kt << 6;
    f32x4 st[4] = {};
#pragma unroll
    for (int kf = 0; kf < 4; ++kf) {
      const size_t ko = (size_t)(kb + kf * 16 + l15) * 64 + lg * 8;
      const bf16x8v kh0 = *(const bf16x8v*)(kh_p + ko);
      const bf16x8v kh1 = *(const bf16x8v*)(kh_p + ko + 32);
      const bf16x8v kl0 = *(const bf16x8v*)(kl_p + ko);
      const bf16x8v kl1 = *(const bf16x8v*)(kl_p + ko + 32);
      f32x4 a = st[kf];
      a = MFMA_BF16(kh0, qfh[0], a);
      a = MFMA_BF16(kh1, qfh[1], a);
      a = MFMA_BF16(kh0, qfl[0], a);
      a = MFMA_BF16(kh1, qfl[1], a);
      a = MFMA_BF16(kl0, qfh[0], a);
      a = MFMA_BF16(kl1, qfh[1], a);
      st[kf] = a;
    }
    if (kt == nfull) {                      // causal mask, diagonal tile only
#pragma unroll
      for (int kf = 0; kf < 4; ++kf)
#pragma unroll
        for (int e = 0; e < 4; ++e) {
          const int key = kb + kf * 16 + (lg << 2) + e;
          const int qr  = qbase + l15;
          if (key > qr) st[kf][e] = -3.0e38f;
        }
    }
    float tmax = -3.0e38f;
#pragma unroll
    for (int kf = 0; kf < 4; ++kf)
#pragma unroll
      for (int e = 0; e < 4; ++e) tmax = fmaxf(tmax, st[kf][e]);
    tmax = fmaxf(tmax, __shfl_xor(tmax, 16));
    tmax = fmaxf(tmax, __shfl_xor(tmax, 32));
    if (!__all(tmax <= mrun + 8.0f)) {      // defer-max
      const float mn = fmaxf(mrun, tmax);
      const float sfac = exp2f((mrun - mn) * L2E);
      mrun = mn;
#pragma unroll
      for (int e = 0; e < 4; ++e) {
        const float so = __shfl(sfac, (lg << 2) + e);
        oden[e] *= so;
#pragma unroll
        for (int df = 0; df < 4; ++df) oac[df][e] *= so;
      }
    }
    const float mL = mrun * L2E;
#pragma unroll
    for (int kf = 0; kf < 4; ++kf) {
      ushort4 pk;
      unsigned short* pp = &pk.x;
#pragma unroll
      for (int e = 0; e < 4; ++e)
        pp[e] = bf_bits(exp2f(fmaf(st[kf][e], L2E, -mL)));
      *(ushort4*)&Plds[l15][kf * 16 + (lg << 2)] = pk;
    }
    // cross-lane LDS handoff fence: lgkmcnt(0) only (no vmcnt drain)
    asm volatile("s_waitcnt lgkmcnt(0)" ::: "memory");
    __builtin_amdgcn_sched_barrier(0);
    bf16x8v pa[2];
#pragma unroll
    for (int x2 = 0; x2 < 2; ++x2)
      pa[x2] = *(const bf16x8v*)&Plds[l15][x2 * 32 + lg * 8];
    asm volatile("" ::: "memory");
#pragma unroll
    for (int x2 = 0; x2 < 2; ++x2) {
      oden = MFMA_BF16(pa[x2], ones8, oden);
#pragma unroll
      for (int df = 0; df < 4; ++df) {
        const bf16x8v vb =
            *(const bf16x8v*)(v_p + (size_t)(df * 16 + l15) * 2048 + kb + x2 * 32 + lg * 8);
        oac[df] = MFMA_BF16(pa[x2], vb, oac[df]);
      }
    }
  }
  float li[4];
#pragma unroll
  for (int e = 0; e < 4; ++e) li[e] = 1.0f / oden[e];
#pragma unroll
  for (int df = 0; df < 4; ++df)
#pragma unroll
    for (int e = 0; e < 4; ++e) {
      const int qr = qbase + (lg << 2) + e;
      const int dh = df * 16 + l15;
      Yp[(size_t)(b * 2048 + qr) * 1024 + h * 64 + dh] =
          __float2bfloat16(oac[df][e] * li[e]);
    }
}

// ----------------------------------------------------------------- gemm_out --
// Y = Yp @ Wo^T, M=4096 N=1024 K=1024. 64x128 tiles -> 512 blocks (2/CU).
__global__ __launch_bounds__(256) void gemm_out(const bf16* __restrict__ A,
                                                const bf16* __restrict__ B,
                                                float* __restrict__ C) {
  const int K = 1024;
  const int NT = 8;  // 1024/128
  __shared__ __attribute__((aligned(16))) bf16 As[2048], Bs[4096];
  const int t = threadIdx.x;
  const int lane = t & 63;
  const int wave = t >> 6;
  const int wr = wave >> 1, wc = wave & 1;   // wave tile 32x64
  int bid = blockIdx.x;
  bid = (bid & 7) * (512 >> 3) + (bid >> 3); // bijective XCD swizzle
  const int bm = bid / NT, bn = bid % NT;
  const int brow = bm * 64, bcol = bn * 128;
  const bf16* pA = A + (size_t)brow * K;
  const bf16* pB = B + (size_t)bcol * K;
  const int r0 = t >> 2;
  const int c0 = (t & 3) * 8;
  f32x4 acc[2][4] = {};
  for (int k0 = 0; k0 < K; k0 += 32) {
    __syncthreads();
    GLD_LDS16(pA + (size_t)r0 * K + k0 + c0,        &As[t * 8]);
    GLD_LDS16(pB + (size_t)r0 * K + k0 + c0,        &Bs[t * 8]);
    GLD_LDS16(pB + (size_t)(r0 + 64) * K + k0 + c0, &Bs[2048 + t * 8]);
    __syncthreads();
    bf16x8v af[2], bf_[4];
    const int l15 = lane & 15, lg = lane >> 4;
#pragma unroll
    for (int i = 0; i < 2; ++i)
      af[i] = *(const bf16x8v*)&As[(wr * 32 + i * 16 + l15) * 32 + lg * 8];
#pragma unroll
    for (int j = 0; j < 4; ++j) {
      const int rB = wc * 64 + j * 16 + l15;
      bf_[j] = *(const bf16x8v*)&Bs[(rB & 63) * 32 + (rB >> 6) * 2048 + lg * 8];
    }
#pragma unroll
    for (int i = 0; i < 2; ++i)
#pragma unroll
      for (int j = 0; j < 4; ++j)
        acc[i][j] = MFMA_BF16(af[i], bf_[j], acc[i][j]);
  }
#pragma unroll
  for (int i = 0; i < 2; ++i)
#pragma unroll
    for (int j = 0; j < 4; ++j)
#pragma unroll
      for (int e = 0; e < 4; ++e) {
        const int m = brow + wr * 32 + i * 16 + ((lane >> 4) << 2) + e;
        const int n = bcol + wc * 64 + j * 16 + (lane & 15);
        C[(size_t)m * 1024 + n] = acc[i][j][e];
      }
}

// -------------------------------------------------------------------- launch --
extern "C" void kernel_launch(void* const* d_in, const int* in_sizes, int n_in,
                              void* d_out, int out_size, void* d_ws, size_t ws_size,
                              hipStream_t stream) {
  (void)in_sizes; (void)n_in; (void)out_size; (void)ws_size;
  const float* x    = (const float*)d_in[0];
  const float* wqkv = (const float*)d_in[1];
  const float* wo   = (const float*)d_in[2];
  float* out = (float*)d_out;

  const size_t NX = 4096ull * 1024;
  const size_t NW = 3072ull * 1024;
  const size_t NO = 1024ull * 1024;

  bf16* p = (bf16*)d_ws;
  bf16* xh  = p; p += NX;
  bf16* xl  = p; p += NX;
  bf16* wqh = p; p += NW;
  bf16* wql = p; p += NW;
  bf16* wob = p; p += NO;
  bf16* qhi = p; p += NX;
  bf16* qlo = p; p += NX;
  bf16* khi = p; p += NX;
  bf16* klo = p; p += NX;
  bf16* vt  = p; p += NX;
  bf16* yp  = p; p += NX;

  hipLaunchKernelGGL(cvt_split, dim3(NX / 1024), dim3(256), 0, stream, x, xh, xl, (int)NX);
  hipLaunchKernelGGL(cvt_split, dim3(NW / 1024), dim3(256), 0, stream, wqkv, wqh, wql, (int)NW);
  hipLaunchKernelGGL(cvt_plain, dim3(NO / 1024), dim3(256), 0, stream, wo, wob, (int)NO);
  hipLaunchKernelGGL(gemm_qkv, dim3(32 * 24), dim3(256), 0, stream,
                     xh, xl, wqh, wql, qhi, qlo, khi, klo, vt);
  hipLaunchKernelGGL(attn_kernel, dim3(4096), dim3(64), 0, stream,
                     qhi, qlo, khi, klo, vt, yp);
  hipLaunchKernelGGL(gemm_out, dim3(64 * 8), dim3(256), 0, stream, yp, wob, out);
}

// Round 9
// 362.029 us; speedup vs baseline: 1.0982x; 1.0982x over previous
//
#include <hip/hip_runtime.h>
#include <hip/hip_bf16.h>

// CustomMHA (B=2,S=2048,D=1024,H=16,dh=64) for MI355X / gfx950.
//
//  1) cvt_split:  x, W_qkv f32 -> (hi,lo) bf16 pairs; W_o -> bf16.
//  2) gemm_qkv :  T = X @ Wqkv^T, split-bf16 (3 MFMA); pure-V col tiles plain.
//     2-phase double-buffered LDS staging with counted vmcnt.
//  3) attn      :  K-SPLIT blocks: 128 thr = 2 waves sharing one (bh, 32-row
//     q-chunk); wave0 = first half of k-tiles, wave1 = rest (incl. diagonal).
//     QBLK=32 per wave, 4096 waves, VGPR<=128 (K/V at use; TLP hides latency).
//     LDS merge of (m, den, O) partials — merge factors are COLUMN-indexed
//     (per l15) and must be __shfl-broadcast to ROW positions (lg*4+e) before
//     scaling the C-layout accumulators (round-8 bug).
//  4) gemm_out :  Y = Yp @ Wo^T, 64x128 tiles (512 blocks), f32 out.

using bf16 = __hip_bfloat16;
typedef __attribute__((ext_vector_type(8))) short bf16x8v;   // 8 bf16 in 4 VGPRs
typedef __attribute__((ext_vector_type(4))) float f32x4;

#define MFMA_BF16(A, B, C) __builtin_amdgcn_mfma_f32_16x16x32_bf16((A), (B), (C), 0, 0, 0)

#define GLD_LDS16(g, l)                                                        \
  __builtin_amdgcn_global_load_lds(                                            \
      (const __attribute__((address_space(1))) void*)(g),                      \
      (__attribute__((address_space(3))) void*)(l), 16, 0, 0)

static __device__ __forceinline__ unsigned short bf_bits(float f) {
  bf16 b = __float2bfloat16(f);
  return *reinterpret_cast<unsigned short*>(&b);
}

// ---------------------------------------------------------------- converts --
__global__ __launch_bounds__(256) void cvt_split(const float* __restrict__ in,
                                                 bf16* __restrict__ hi,
                                                 bf16* __restrict__ lo, int n) {
  int i = (blockIdx.x * 256 + threadIdx.x) * 4;
  if (i >= n) return;
  const float4 v = *(const float4*)(in + i);
  float vv[4] = {v.x, v.y, v.z, v.w};
  ushort4 hb, lb;
  unsigned short* hp = &hb.x;
  unsigned short* lp = &lb.x;
#pragma unroll
  for (int j = 0; j < 4; ++j) {
    bf16 h = __float2bfloat16(vv[j]);
    float r = vv[j] - __bfloat162float(h);
    hp[j] = bf_bits(vv[j]);
    lp[j] = bf_bits(r);
  }
  *(ushort4*)(hi + i) = hb;
  *(ushort4*)(lo + i) = lb;
}

__global__ __launch_bounds__(256) void cvt_plain(const float* __restrict__ in,
                                                 bf16* __restrict__ out, int n) {
  int i = (blockIdx.x * 256 + threadIdx.x) * 4;
  if (i >= n) return;
  const float4 v = *(const float4*)(in + i);
  ushort4 ob;
  ob.x = bf_bits(v.x); ob.y = bf_bits(v.y); ob.z = bf_bits(v.z); ob.w = bf_bits(v.w);
  *(ushort4*)(out + i) = ob;
}

// ----------------------------------------------------------------- gemm_qkv --
// 128x128 tile, 256 thr (4 waves 2x2), BK=32, 2-phase dbuf staging.
__global__ __launch_bounds__(256) void gemm_qkv(
    const bf16* __restrict__ Ah, const bf16* __restrict__ Al,
    const bf16* __restrict__ Bh, const bf16* __restrict__ Bl,
    bf16* __restrict__ Qhi, bf16* __restrict__ Qlo,
    bf16* __restrict__ Khi, bf16* __restrict__ Klo,
    bf16* __restrict__ Vt) {
  const int K = 1024;
  const int NT = 24;
  __shared__ __attribute__((aligned(16))) bf16 AsH[2][4096], AsL[2][4096],
                                               BsH[2][4096], BsL[2][4096];
  const int t = threadIdx.x;
  const int lane = t & 63;
  const int wave = t >> 6;
  const int wr = wave >> 1, wc = wave & 1;
  int bid = blockIdx.x;
  bid = (bid & 7) * (768 >> 3) + (bid >> 3);
  const int bm = bid / NT, bn = bid % NT;
  const int brow = bm * 128, bcol = bn * 128;
  const bool isV = (bcol >= 2048);
  const bf16* pAh = Ah + (size_t)brow * K;
  const bf16* pAl = Al + (size_t)brow * K;
  const bf16* pBh = Bh + (size_t)bcol * K;
  const bf16* pBl = Bl + (size_t)bcol * K;
  const int r0 = t >> 2;
  const int c0 = (t & 3) * 8;
  f32x4 acc[4][4] = {};

#define STAGE(buf, k0_)                                                        \
  {                                                                            \
    const int _k = (k0_);                                                      \
    GLD_LDS16(pAh + (size_t)r0 * K + _k + c0,        &AsH[buf][t * 8]);        \
    GLD_LDS16(pAh + (size_t)(r0 + 64) * K + _k + c0, &AsH[buf][2048 + t * 8]); \
    GLD_LDS16(pBh + (size_t)r0 * K + _k + c0,        &BsH[buf][t * 8]);        \
    GLD_LDS16(pBh + (size_t)(r0 + 64) * K + _k + c0, &BsH[buf][2048 + t * 8]); \
    if (!isV) {                                                                \
      GLD_LDS16(pAl + (size_t)r0 * K + _k + c0,        &AsL[buf][t * 8]);      \
      GLD_LDS16(pAl + (size_t)(r0 + 64) * K + _k + c0, &AsL[buf][2048 + t * 8]);\
      GLD_LDS16(pBl + (size_t)r0 * K + _k + c0,        &BsL[buf][t * 8]);      \
      GLD_LDS16(pBl + (size_t)(r0 + 64) * K + _k + c0, &BsL[buf][2048 + t * 8]);\
    }                                                                          \
  }

  STAGE(0, 0);
  const int ao = (wr * 64 + (lane & 15)) * 32 + (lane >> 4) * 8;
  const int bo = (wc * 64 + (lane & 15)) * 32 + (lane >> 4) * 8;
  for (int tk = 0; tk < 32; ++tk) {
    const int cur = tk & 1;
    if (tk < 31) {
      STAGE(cur ^ 1, (tk + 1) * 32);
      if (!isV) asm volatile("s_waitcnt vmcnt(8)" ::: "memory");
      else      asm volatile("s_waitcnt vmcnt(4)" ::: "memory");
    } else {
      asm volatile("s_waitcnt vmcnt(0)" ::: "memory");
    }
    __builtin_amdgcn_sched_barrier(0);
    __builtin_amdgcn_s_barrier();
    asm volatile("" ::: "memory");
    bf16x8v ah[4], bh_[4];
#pragma unroll
    for (int i = 0; i < 4; ++i) {
      ah[i]  = *(const bf16x8v*)&AsH[cur][ao + i * 512];
      bh_[i] = *(const bf16x8v*)&BsH[cur][bo + i * 512];
    }
    if (!isV) {
      bf16x8v al[4], bl_[4];
#pragma unroll
      for (int i = 0; i < 4; ++i) {
        al[i]  = *(const bf16x8v*)&AsL[cur][ao + i * 512];
        bl_[i] = *(const bf16x8v*)&BsL[cur][bo + i * 512];
      }
#pragma unroll
      for (int i = 0; i < 4; ++i)
#pragma unroll
        for (int j = 0; j < 4; ++j) {
          acc[i][j] = MFMA_BF16(ah[i], bh_[j], acc[i][j]);
          acc[i][j] = MFMA_BF16(ah[i], bl_[j], acc[i][j]);
          acc[i][j] = MFMA_BF16(al[i], bh_[j], acc[i][j]);
        }
    } else {
#pragma unroll
      for (int i = 0; i < 4; ++i)
#pragma unroll
        for (int j = 0; j < 4; ++j)
          acc[i][j] = MFMA_BF16(ah[i], bh_[j], acc[i][j]);
    }
    asm volatile("" ::: "memory");
    __builtin_amdgcn_sched_barrier(0);
    __builtin_amdgcn_s_barrier();
    asm volatile("" ::: "memory");
  }
#undef STAGE
#pragma unroll
  for (int i = 0; i < 4; ++i)
#pragma unroll
    for (int j = 0; j < 4; ++j)
#pragma unroll
      for (int e = 0; e < 4; ++e) {
        const int m = brow + wr * 64 + i * 16 + ((lane >> 4) << 2) + e;
        const int n = bcol + wc * 64 + j * 16 + (lane & 15);
        float v = acc[i][j][e];
        const int b = m >> 11, s = m & 2047;
        const int c = n >> 10, d = n & 1023;
        const int bh_i = (b << 4) | (s >> 7);
        const int s2 = ((s & 127) << 4) | (d >> 6);
        const int dh = d & 63;
        if (c == 2) {
          Vt[((size_t)bh_i << 17) | ((size_t)dh << 11) | (size_t)s2] = __float2bfloat16(v);
        } else {
          if (c == 0) v *= 0.03125f;
          const size_t idx = ((size_t)bh_i << 17) | ((size_t)s2 << 6) | (size_t)dh;
          bf16 hv = __float2bfloat16(v);
          bf16 lv = __float2bfloat16(v - __bfloat162float(hv));
          if (c == 0) { Qhi[idx] = hv; Qlo[idx] = lv; }
          else        { Khi[idx] = hv; Klo[idx] = lv; }
        }
      }
}

// --------------------------------------------------------------------- attn --
// 2048 blocks x 128 thr: 2 waves split the k-tiles of one (bh, 32-row chunk).
__global__ __launch_bounds__(128, 4) void attn_kernel(
    const bf16* __restrict__ Qhi, const bf16* __restrict__ Qlo,
    const bf16* __restrict__ Khi, const bf16* __restrict__ Klo,
    const bf16* __restrict__ Vt, bf16* __restrict__ Yp) {
  const int lane = threadIdx.x & 63;
  const int wv   = threadIdx.x >> 6;       // k-split half (0 or 1)
  const int bh = blockIdx.x & 31;          // bh minor (bh%8 pins the XCD)
  const int c  = 63 - (blockIdx.x >> 5);   // chunk, longest first
  const int b = bh >> 4, h = bh & 15;
  const size_t base = (size_t)bh << 17;
  const bf16* qh_p = Qhi + base;
  const bf16* ql_p = Qlo + base;
  const bf16* kh_p = Khi + base;
  const bf16* kl_p = Klo + base;
  const bf16* v_p  = Vt + base;            // (dh, s2) layout
  const int qbase = c << 5;
  const int l15 = lane & 15;
  const int lg  = lane >> 4;

  // Shared: per-wave P scratch ([32][72] bf16 = 4608 B each) unioned with the
  // cross-wave merge buffer (64 lanes x 44 f32 = 11264 B).
  __shared__ __attribute__((aligned(16))) float Xch[64][44];
  bf16* Plds = reinterpret_cast<bf16*>(&Xch[0][0]) + wv * 2304;  // [32][72]

  bf16x8v qfh[2][2], qfl[2][2];
#pragma unroll
  for (int q2 = 0; q2 < 2; ++q2)
#pragma unroll
    for (int x2 = 0; x2 < 2; ++x2) {
      const size_t o = (size_t)(qbase + q2 * 16 + l15) * 64 + x2 * 32 + lg * 8;
      qfh[q2][x2] = *(const bf16x8v*)(qh_p + o);
      qfl[q2][x2] = *(const bf16x8v*)(ql_p + o);
    }
  bf16x8v ones8;
#pragma unroll
  for (int j = 0; j < 8; ++j) ones8[j] = (short)0x3F80;

  f32x4 oac[2][4] = {};
  f32x4 oden[2] = {};
  float mrun[2] = {-3.0e38f, -3.0e38f};
  const float L2E = 1.4426950408889634f;
  const int n  = (c >> 1) + 1;             // total k-tiles for this chunk
  const int h0 = (n + 1) >> 1;             // wave0: [0,h0)  wave1: [h0,n)
  const int kt0 = wv ? h0 : 0;
  const int kt1 = wv ? n : h0;
  const int diag = n - 1;

  for (int kt = kt0; kt < kt1; ++kt) {
    const int kb = kt << 6;
    f32x4 st[4][2] = {};
#pragma unroll
    for (int kf = 0; kf < 4; ++kf) {
      const size_t ko = (size_t)(kb + kf * 16 + l15) * 64 + lg * 8;
      const bf16x8v kh0 = *(const bf16x8v*)(kh_p + ko);
      const bf16x8v kh1 = *(const bf16x8v*)(kh_p + ko + 32);
      const bf16x8v kl0 = *(const bf16x8v*)(kl_p + ko);
      const bf16x8v kl1 = *(const bf16x8v*)(kl_p + ko + 32);
#pragma unroll
      for (int q2 = 0; q2 < 2; ++q2) {
        f32x4 a = st[kf][q2];
        a = MFMA_BF16(kh0, qfh[q2][0], a);
        a = MFMA_BF16(kh1, qfh[q2][1], a);
        a = MFMA_BF16(kh0, qfl[q2][0], a);
        a = MFMA_BF16(kh1, qfl[q2][1], a);
        a = MFMA_BF16(kl0, qfh[q2][0], a);
        a = MFMA_BF16(kl1, qfh[q2][1], a);
        st[kf][q2] = a;
      }
    }
    if (kt == diag) {                      // causal mask, diagonal tile only
#pragma unroll
      for (int kf = 0; kf < 4; ++kf)
#pragma unroll
        for (int q2 = 0; q2 < 2; ++q2)
#pragma unroll
          for (int e = 0; e < 4; ++e) {
            const int key = kb + kf * 16 + (lg << 2) + e;
            const int qr  = qbase + q2 * 16 + l15;
            if (key > qr) st[kf][q2][e] = -3.0e38f;
          }
    }
    float tmax[2] = {-3.0e38f, -3.0e38f};
#pragma unroll
    for (int kf = 0; kf < 4; ++kf)
#pragma unroll
      for (int q2 = 0; q2 < 2; ++q2)
#pragma unroll
        for (int e = 0; e < 4; ++e)
          tmax[q2] = fmaxf(tmax[q2], st[kf][q2][e]);
#pragma unroll
    for (int q2 = 0; q2 < 2; ++q2) {
      tmax[q2] = fmaxf(tmax[q2], __shfl_xor(tmax[q2], 16));
      tmax[q2] = fmaxf(tmax[q2], __shfl_xor(tmax[q2], 32));
    }
    const int ok = (tmax[0] <= mrun[0] + 8.0f) && (tmax[1] <= mrun[1] + 8.0f);
    if (!__all(ok)) {
      float sfac[2];
#pragma unroll
      for (int q2 = 0; q2 < 2; ++q2) {
        const float mn = fmaxf(mrun[q2], tmax[q2]);
        sfac[q2] = exp2f((mrun[q2] - mn) * L2E);
        mrun[q2] = mn;
      }
#pragma unroll
      for (int q2 = 0; q2 < 2; ++q2)
#pragma unroll
        for (int e = 0; e < 4; ++e) {
          const float so = __shfl(sfac[q2], (lg << 2) + e);  // col -> row bcast
          oden[q2][e] *= so;
#pragma unroll
          for (int df = 0; df < 4; ++df) oac[q2][df][e] *= so;
        }
    }
    const float mL0 = mrun[0] * L2E, mL1 = mrun[1] * L2E;
#pragma unroll
    for (int kf = 0; kf < 4; ++kf)
#pragma unroll
      for (int q2 = 0; q2 < 2; ++q2) {
        const float mL = q2 ? mL1 : mL0;
        ushort4 pk;
        unsigned short* pp = &pk.x;
#pragma unroll
        for (int e = 0; e < 4; ++e)
          pp[e] = bf_bits(exp2f(fmaf(st[kf][q2][e], L2E, -mL)));
        *(ushort4*)(Plds + (q2 * 16 + l15) * 72 + kf * 16 + (lg << 2)) = pk;
      }
    // Issue V loads (vmcnt) so they fly under the lgkm fence + P reads.
    bf16x8v vreg[2][4];
#pragma unroll
    for (int x2 = 0; x2 < 2; ++x2)
#pragma unroll
      for (int df = 0; df < 4; ++df)
        vreg[x2][df] =
            *(const bf16x8v*)(v_p + (size_t)(df * 16 + l15) * 2048 + kb + x2 * 32 + lg * 8);
    // cross-lane (within-wave) LDS handoff fence: lgkmcnt(0) only.
    asm volatile("s_waitcnt lgkmcnt(0)" ::: "memory");
    __builtin_amdgcn_sched_barrier(0);
    bf16x8v pa[2][2];
#pragma unroll
    for (int x2 = 0; x2 < 2; ++x2)
#pragma unroll
      for (int q2 = 0; q2 < 2; ++q2)
        pa[x2][q2] = *(const bf16x8v*)(Plds + (q2 * 16 + l15) * 72 + x2 * 32 + lg * 8);
    asm volatile("" ::: "memory");
#pragma unroll
    for (int x2 = 0; x2 < 2; ++x2) {
#pragma unroll
      for (int q2 = 0; q2 < 2; ++q2)
        oden[q2] = MFMA_BF16(pa[x2][q2], ones8, oden[q2]);
#pragma unroll
      for (int df = 0; df < 4; ++df)
#pragma unroll
        for (int q2 = 0; q2 < 2; ++q2)
          oac[q2][df] = MFMA_BF16(pa[x2][q2], vreg[x2][df], oac[q2][df]);
    }
  }

  // ---- cross-wave merge: wave1 publishes partials, wave0 combines+writes ----
  __syncthreads();
  if (wv == 1) {
    float* dst = &Xch[lane][0];
    dst[0] = mrun[0];
    dst[1] = mrun[1];
#pragma unroll
    for (int q2 = 0; q2 < 2; ++q2)
#pragma unroll
      for (int e = 0; e < 4; ++e) dst[2 + q2 * 4 + e] = oden[q2][e];
#pragma unroll
    for (int q2 = 0; q2 < 2; ++q2)
#pragma unroll
      for (int df = 0; df < 4; ++df)
#pragma unroll
        for (int e = 0; e < 4; ++e)
          dst[10 + q2 * 16 + df * 4 + e] = oac[q2][df][e];
  }
  __syncthreads();
  if (wv == 0) {
    const float* src = &Xch[lane][0];
#pragma unroll
    for (int q2 = 0; q2 < 2; ++q2) {
      // COLUMN-indexed (per l15) merge factors...
      const float m1 = src[q2];
      const float mm = fmaxf(mrun[q2], m1);
      const float f0c = exp2f((mrun[q2] - mm) * L2E);
      const float f1c = exp2f((m1 - mm) * L2E);
#pragma unroll
      for (int e = 0; e < 4; ++e) {
        // ...broadcast to ROW positions (accumulator row = lg*4+e) before use.
        const float f0 = __shfl(f0c, (lg << 2) + e);
        const float f1 = __shfl(f1c, (lg << 2) + e);
        oden[q2][e] = oden[q2][e] * f0 + src[2 + q2 * 4 + e] * f1;
#pragma unroll
        for (int df = 0; df < 4; ++df)
          oac[q2][df][e] = oac[q2][df][e] * f0 + src[10 + q2 * 16 + df * 4 + e] * f1;
      }
    }
#pragma unroll
    for (int q2 = 0; q2 < 2; ++q2) {
      float li[4];
#pragma unroll
      for (int e = 0; e < 4; ++e) li[e] = 1.0f / oden[q2][e];
#pragma unroll
      for (int df = 0; df < 4; ++df)
#pragma unroll
        for (int e = 0; e < 4; ++e) {
          const int qr = qbase + q2 * 16 + (lg << 2) + e;
          const int dh = df * 16 + l15;
          Yp[(size_t)(b * 2048 + qr) * 1024 + h * 64 + dh] =
              __float2bfloat16(oac[q2][df][e] * li[e]);
        }
    }
  }
}

// ----------------------------------------------------------------- gemm_out --
// Y = Yp @ Wo^T, M=4096 N=1024 K=1024. 64x128 tiles -> 512 blocks (2/CU).
__global__ __launch_bounds__(256) void gemm_out(const bf16* __restrict__ A,
                                                const bf16* __restrict__ B,
                                                float* __restrict__ C) {
  const int K = 1024;
  const int NT = 8;
  __shared__ __attribute__((aligned(16))) bf16 As[2048], Bs[4096];
  const int t = threadIdx.x;
  const int lane = t & 63;
  const int wave = t >> 6;
  const int wr = wave >> 1, wc = wave & 1;
  int bid = blockIdx.x;
  bid = (bid & 7) * (512 >> 3) + (bid >> 3);
  const int bm = bid / NT, bn = bid % NT;
  const int brow = bm * 64, bcol = bn * 128;
  const bf16* pA = A + (size_t)brow * K;
  const bf16* pB = B + (size_t)bcol * K;
  const int r0 = t >> 2;
  const int c0 = (t & 3) * 8;
  f32x4 acc[2][4] = {};
  for (int k0 = 0; k0 < K; k0 += 32) {
    __syncthreads();
    GLD_LDS16(pA + (size_t)r0 * K + k0 + c0,        &As[t * 8]);
    GLD_LDS16(pB + (size_t)r0 * K + k0 + c0,        &Bs[t * 8]);
    GLD_LDS16(pB + (size_t)(r0 + 64) * K + k0 + c0, &Bs[2048 + t * 8]);
    __syncthreads();
    bf16x8v af[2], bf_[4];
    const int l15 = lane & 15, lg = lane >> 4;
#pragma unroll
    for (int i = 0; i < 2; ++i)
      af[i] = *(const bf16x8v*)&As[(wr * 32 + i * 16 + l15) * 32 + lg * 8];
#pragma unroll
    for (int j = 0; j < 4; ++j) {
      const int rB = wc * 64 + j * 16 + l15;
      bf_[j] = *(const bf16x8v*)&Bs[(rB & 63) * 32 + (rB >> 6) * 2048 + lg * 8];
    }
#pragma unroll
    for (int i = 0; i < 2; ++i)
#pragma unroll
      for (int j = 0; j < 4; ++j)
        acc[i][j] = MFMA_BF16(af[i], bf_[j], acc[i][j]);
  }
#pragma unroll
  for (int i = 0; i < 2; ++i)
#pragma unroll
    for (int j = 0; j < 4; ++j)
#pragma unroll
      for (int e = 0; e < 4; ++e) {
        const int m = brow + wr * 32 + i * 16 + ((lane >> 4) << 2) + e;
        const int n = bcol + wc * 64 + j * 16 + (lane & 15);
        C[(size_t)m * 1024 + n] = acc[i][j][e];
      }
}

// -------------------------------------------------------------------- launch --
extern "C" void kernel_launch(void* const* d_in, const int* in_sizes, int n_in,
                              void* d_out, int out_size, void* d_ws, size_t ws_size,
                              hipStream_t stream) {
  (void)in_sizes; (void)n_in; (void)out_size; (void)ws_size;
  const float* x    = (const float*)d_in[0];
  const float* wqkv = (const float*)d_in[1];
  const float* wo   = (const float*)d_in[2];
  float* out = (float*)d_out;

  const size_t NX = 4096ull * 1024;
  const size_t NW = 3072ull * 1024;
  const size_t NO = 1024ull * 1024;

  bf16* p = (bf16*)d_ws;
  bf16* xh  = p; p += NX;
  bf16* xl  = p; p += NX;
  bf16* wqh = p; p += NW;
  bf16* wql = p; p += NW;
  bf16* wob = p; p += NO;
  bf16* qhi = p; p += NX;
  bf16* qlo = p; p += NX;
  bf16* khi = p; p += NX;
  bf16* klo = p; p += NX;
  bf16* vt  = p; p += NX;
  bf16* yp  = p; p += NX;

  hipLaunchKernelGGL(cvt_split, dim3(NX / 1024), dim3(256), 0, stream, x, xh, xl, (int)NX);
  hipLaunchKernelGGL(cvt_split, dim3(NW / 1024), dim3(256), 0, stream, wqkv, wqh, wql, (int)NW);
  hipLaunchKernelGGL(cvt_plain, dim3(NO / 1024), dim3(256), 0, stream, wo, wob, (int)NO);
  hipLaunchKernelGGL(gemm_qkv, dim3(32 * 24), dim3(256), 0, stream,
                     xh, xl, wqh, wql, qhi, qlo, khi, klo, vt);
  hipLaunchKernelGGL(attn_kernel, dim3(2048), dim3(128), 0, stream,
                     qhi, qlo, khi, klo, vt, yp);
  hipLaunchKernelGGL(gemm_out, dim3(64 * 8), dim3(256), 0, stream, yp, wob, out);
}

// Round 10
// 313.079 us; speedup vs baseline: 1.2699x; 1.1564x over previous
//
#include <hip/hip_runtime.h>
#include <hip/hip_bf16.h>

// CustomMHA (B=2,S=2048,D=1024,H=16,dh=64) for MI355X / gfx950.
//
//  1) cvt_split:  x, W_qkv f32 -> (hi,lo) bf16 pairs; W_o -> bf16.
//  2) gemm_qkv :  T = X @ Wqkv^T, split-bf16 (3 MFMA); pure-V col tiles plain.
//     2-phase double-buffered LDS staging with counted vmcnt.
//  3) attn      :  K-SPLIT blocks: 128 thr = 2 waves sharing one (bh, 32-row
//     q-chunk); wave0 = first half of k-tiles, wave1 = rest (incl. diagonal).
//     QBLK=32 per wave, 4096 waves. __launch_bounds__(128,2): round-9's
//     (128,4) made hipcc cap VGPR at 64 (8 waves/EU for 2-wave blocks) ->
//     ~150 MB of scratch spill traffic each way. (128,2) caps at >=128;
//     live state ~125 VGPRs fits, spills vanish.
//  4) gemm_out :  Y = Yp @ Wo^T, 64x128 tiles (512 blocks), f32 out.

using bf16 = __hip_bfloat16;
typedef __attribute__((ext_vector_type(8))) short bf16x8v;   // 8 bf16 in 4 VGPRs
typedef __attribute__((ext_vector_type(4))) float f32x4;

#define MFMA_BF16(A, B, C) __builtin_amdgcn_mfma_f32_16x16x32_bf16((A), (B), (C), 0, 0, 0)

#define GLD_LDS16(g, l)                                                        \
  __builtin_amdgcn_global_load_lds(                                            \
      (const __attribute__((address_space(1))) void*)(g),                      \
      (__attribute__((address_space(3))) void*)(l), 16, 0, 0)

static __device__ __forceinline__ unsigned short bf_bits(float f) {
  bf16 b = __float2bfloat16(f);
  return *reinterpret_cast<unsigned short*>(&b);
}

// ---------------------------------------------------------------- converts --
__global__ __launch_bounds__(256) void cvt_split(const float* __restrict__ in,
                                                 bf16* __restrict__ hi,
                                                 bf16* __restrict__ lo, int n) {
  int i = (blockIdx.x * 256 + threadIdx.x) * 4;
  if (i >= n) return;
  const float4 v = *(const float4*)(in + i);
  float vv[4] = {v.x, v.y, v.z, v.w};
  ushort4 hb, lb;
  unsigned short* hp = &hb.x;
  unsigned short* lp = &lb.x;
#pragma unroll
  for (int j = 0; j < 4; ++j) {
    bf16 h = __float2bfloat16(vv[j]);
    float r = vv[j] - __bfloat162float(h);
    hp[j] = bf_bits(vv[j]);
    lp[j] = bf_bits(r);
  }
  *(ushort4*)(hi + i) = hb;
  *(ushort4*)(lo + i) = lb;
}

__global__ __launch_bounds__(256) void cvt_plain(const float* __restrict__ in,
                                                 bf16* __restrict__ out, int n) {
  int i = (blockIdx.x * 256 + threadIdx.x) * 4;
  if (i >= n) return;
  const float4 v = *(const float4*)(in + i);
  ushort4 ob;
  ob.x = bf_bits(v.x); ob.y = bf_bits(v.y); ob.z = bf_bits(v.z); ob.w = bf_bits(v.w);
  *(ushort4*)(out + i) = ob;
}

// ----------------------------------------------------------------- gemm_qkv --
// 128x128 tile, 256 thr (4 waves 2x2), BK=32, 2-phase dbuf staging.
__global__ __launch_bounds__(256) void gemm_qkv(
    const bf16* __restrict__ Ah, const bf16* __restrict__ Al,
    const bf16* __restrict__ Bh, const bf16* __restrict__ Bl,
    bf16* __restrict__ Qhi, bf16* __restrict__ Qlo,
    bf16* __restrict__ Khi, bf16* __restrict__ Klo,
    bf16* __restrict__ Vt) {
  const int K = 1024;
  const int NT = 24;
  __shared__ __attribute__((aligned(16))) bf16 AsH[2][4096], AsL[2][4096],
                                               BsH[2][4096], BsL[2][4096];
  const int t = threadIdx.x;
  const int lane = t & 63;
  const int wave = t >> 6;
  const int wr = wave >> 1, wc = wave & 1;
  int bid = blockIdx.x;
  bid = (bid & 7) * (768 >> 3) + (bid >> 3);
  const int bm = bid / NT, bn = bid % NT;
  const int brow = bm * 128, bcol = bn * 128;
  const bool isV = (bcol >= 2048);
  const bf16* pAh = Ah + (size_t)brow * K;
  const bf16* pAl = Al + (size_t)brow * K;
  const bf16* pBh = Bh + (size_t)bcol * K;
  const bf16* pBl = Bl + (size_t)bcol * K;
  const int r0 = t >> 2;
  const int c0 = (t & 3) * 8;
  f32x4 acc[4][4] = {};

#define STAGE(buf, k0_)                                                        \
  {                                                                            \
    const int _k = (k0_);                                                      \
    GLD_LDS16(pAh + (size_t)r0 * K + _k + c0,        &AsH[buf][t * 8]);        \
    GLD_LDS16(pAh + (size_t)(r0 + 64) * K + _k + c0, &AsH[buf][2048 + t * 8]); \
    GLD_LDS16(pBh + (size_t)r0 * K + _k + c0,        &BsH[buf][t * 8]);        \
    GLD_LDS16(pBh + (size_t)(r0 + 64) * K + _k + c0, &BsH[buf][2048 + t * 8]); \
    if (!isV) {                                                                \
      GLD_LDS16(pAl + (size_t)r0 * K + _k + c0,        &AsL[buf][t * 8]);      \
      GLD_LDS16(pAl + (size_t)(r0 + 64) * K + _k + c0, &AsL[buf][2048 + t * 8]);\
      GLD_LDS16(pBl + (size_t)r0 * K + _k + c0,        &BsL[buf][t * 8]);      \
      GLD_LDS16(pBl + (size_t)(r0 + 64) * K + _k + c0, &BsL[buf][2048 + t * 8]);\
    }                                                                          \
  }

  STAGE(0, 0);
  const int ao = (wr * 64 + (lane & 15)) * 32 + (lane >> 4) * 8;
  const int bo = (wc * 64 + (lane & 15)) * 32 + (lane >> 4) * 8;
  for (int tk = 0; tk < 32; ++tk) {
    const int cur = tk & 1;
    if (tk < 31) {
      STAGE(cur ^ 1, (tk + 1) * 32);
      if (!isV) asm volatile("s_waitcnt vmcnt(8)" ::: "memory");
      else      asm volatile("s_waitcnt vmcnt(4)" ::: "memory");
    } else {
      asm volatile("s_waitcnt vmcnt(0)" ::: "memory");
    }
    __builtin_amdgcn_sched_barrier(0);
    __builtin_amdgcn_s_barrier();
    asm volatile("" ::: "memory");
    bf16x8v ah[4], bh_[4];
#pragma unroll
    for (int i = 0; i < 4; ++i) {
      ah[i]  = *(const bf16x8v*)&AsH[cur][ao + i * 512];
      bh_[i] = *(const bf16x8v*)&BsH[cur][bo + i * 512];
    }
    if (!isV) {
      bf16x8v al[4], bl_[4];
#pragma unroll
      for (int i = 0; i < 4; ++i) {
        al[i]  = *(const bf16x8v*)&AsL[cur][ao + i * 512];
        bl_[i] = *(const bf16x8v*)&BsL[cur][bo + i * 512];
      }
#pragma unroll
      for (int i = 0; i < 4; ++i)
#pragma unroll
        for (int j = 0; j < 4; ++j) {
          acc[i][j] = MFMA_BF16(ah[i], bh_[j], acc[i][j]);
          acc[i][j] = MFMA_BF16(ah[i], bl_[j], acc[i][j]);
          acc[i][j] = MFMA_BF16(al[i], bh_[j], acc[i][j]);
        }
    } else {
#pragma unroll
      for (int i = 0; i < 4; ++i)
#pragma unroll
        for (int j = 0; j < 4; ++j)
          acc[i][j] = MFMA_BF16(ah[i], bh_[j], acc[i][j]);
    }
    asm volatile("" ::: "memory");
    __builtin_amdgcn_sched_barrier(0);
    __builtin_amdgcn_s_barrier();
    asm volatile("" ::: "memory");
  }
#undef STAGE
#pragma unroll
  for (int i = 0; i < 4; ++i)
#pragma unroll
    for (int j = 0; j < 4; ++j)
#pragma unroll
      for (int e = 0; e < 4; ++e) {
        const int m = brow + wr * 64 + i * 16 + ((lane >> 4) << 2) + e;
        const int n = bcol + wc * 64 + j * 16 + (lane & 15);
        float v = acc[i][j][e];
        const int b = m >> 11, s = m & 2047;
        const int c = n >> 10, d = n & 1023;
        const int bh_i = (b << 4) | (s >> 7);
        const int s2 = ((s & 127) << 4) | (d >> 6);
        const int dh = d & 63;
        if (c == 2) {
          Vt[((size_t)bh_i << 17) | ((size_t)dh << 11) | (size_t)s2] = __float2bfloat16(v);
        } else {
          if (c == 0) v *= 0.03125f;
          const size_t idx = ((size_t)bh_i << 17) | ((size_t)s2 << 6) | (size_t)dh;
          bf16 hv = __float2bfloat16(v);
          bf16 lv = __float2bfloat16(v - __bfloat162float(hv));
          if (c == 0) { Qhi[idx] = hv; Qlo[idx] = lv; }
          else        { Khi[idx] = hv; Klo[idx] = lv; }
        }
      }
}

// --------------------------------------------------------------------- attn --
// 2048 blocks x 128 thr: 2 waves split the k-tiles of one (bh, 32-row chunk).
// launch_bounds(128,2): VGPR cap >=128 so the ~125 live regs do NOT spill.
__global__ __launch_bounds__(128, 2) void attn_kernel(
    const bf16* __restrict__ Qhi, const bf16* __restrict__ Qlo,
    const bf16* __restrict__ Khi, const bf16* __restrict__ Klo,
    const bf16* __restrict__ Vt, bf16* __restrict__ Yp) {
  const int lane = threadIdx.x & 63;
  const int wv   = threadIdx.x >> 6;       // k-split half (0 or 1)
  const int bh = blockIdx.x & 31;          // bh minor (bh%8 pins the XCD)
  const int c  = 63 - (blockIdx.x >> 5);   // chunk, longest first
  const int b = bh >> 4, h = bh & 15;
  const size_t base = (size_t)bh << 17;
  const bf16* qh_p = Qhi + base;
  const bf16* ql_p = Qlo + base;
  const bf16* kh_p = Khi + base;
  const bf16* kl_p = Klo + base;
  const bf16* v_p  = Vt + base;            // (dh, s2) layout
  const int qbase = c << 5;
  const int l15 = lane & 15;
  const int lg  = lane >> 4;

  // Shared: per-wave P scratch ([32][72] bf16 = 4608 B each) unioned with the
  // cross-wave merge buffer (64 lanes x 44 f32 = 11264 B).
  __shared__ __attribute__((aligned(16))) float Xch[64][44];
  bf16* Plds = reinterpret_cast<bf16*>(&Xch[0][0]) + wv * 2304;  // [32][72]

  bf16x8v qfh[2][2], qfl[2][2];
#pragma unroll
  for (int q2 = 0; q2 < 2; ++q2)
#pragma unroll
    for (int x2 = 0; x2 < 2; ++x2) {
      const size_t o = (size_t)(qbase + q2 * 16 + l15) * 64 + x2 * 32 + lg * 8;
      qfh[q2][x2] = *(const bf16x8v*)(qh_p + o);
      qfl[q2][x2] = *(const bf16x8v*)(ql_p + o);
    }
  bf16x8v ones8;
#pragma unroll
  for (int j = 0; j < 8; ++j) ones8[j] = (short)0x3F80;

  f32x4 oac[2][4] = {};
  f32x4 oden[2] = {};
  float mrun[2] = {-3.0e38f, -3.0e38f};
  const float L2E = 1.4426950408889634f;
  const int n  = (c >> 1) + 1;             // total k-tiles for this chunk
  const int h0 = (n + 1) >> 1;             // wave0: [0,h0)  wave1: [h0,n)
  const int kt0 = wv ? h0 : 0;
  const int kt1 = wv ? n : h0;
  const int diag = n - 1;

  for (int kt = kt0; kt < kt1; ++kt) {
    const int kb = kt << 6;
    f32x4 st[4][2] = {};
#pragma unroll
    for (int kf = 0; kf < 4; ++kf) {
      const size_t ko = (size_t)(kb + kf * 16 + l15) * 64 + lg * 8;
      const bf16x8v kh0 = *(const bf16x8v*)(kh_p + ko);
      const bf16x8v kh1 = *(const bf16x8v*)(kh_p + ko + 32);
      const bf16x8v kl0 = *(const bf16x8v*)(kl_p + ko);
      const bf16x8v kl1 = *(const bf16x8v*)(kl_p + ko + 32);
#pragma unroll
      for (int q2 = 0; q2 < 2; ++q2) {
        f32x4 a = st[kf][q2];
        a = MFMA_BF16(kh0, qfh[q2][0], a);
        a = MFMA_BF16(kh1, qfh[q2][1], a);
        a = MFMA_BF16(kh0, qfl[q2][0], a);
        a = MFMA_BF16(kh1, qfl[q2][1], a);
        a = MFMA_BF16(kl0, qfh[q2][0], a);
        a = MFMA_BF16(kl1, qfh[q2][1], a);
        st[kf][q2] = a;
      }
    }
    if (kt == diag) {                      // causal mask, diagonal tile only
#pragma unroll
      for (int kf = 0; kf < 4; ++kf)
#pragma unroll
        for (int q2 = 0; q2 < 2; ++q2)
#pragma unroll
          for (int e = 0; e < 4; ++e) {
            const int key = kb + kf * 16 + (lg << 2) + e;
            const int qr  = qbase + q2 * 16 + l15;
            if (key > qr) st[kf][q2][e] = -3.0e38f;
          }
    }
    float tmax[2] = {-3.0e38f, -3.0e38f};
#pragma unroll
    for (int kf = 0; kf < 4; ++kf)
#pragma unroll
      for (int q2 = 0; q2 < 2; ++q2)
#pragma unroll
        for (int e = 0; e < 4; ++e)
          tmax[q2] = fmaxf(tmax[q2], st[kf][q2][e]);
#pragma unroll
    for (int q2 = 0; q2 < 2; ++q2) {
      tmax[q2] = fmaxf(tmax[q2], __shfl_xor(tmax[q2], 16));
      tmax[q2] = fmaxf(tmax[q2], __shfl_xor(tmax[q2], 32));
    }
    const int ok = (tmax[0] <= mrun[0] + 8.0f) && (tmax[1] <= mrun[1] + 8.0f);
    if (!__all(ok)) {
      float sfac[2];
#pragma unroll
      for (int q2 = 0; q2 < 2; ++q2) {
        const float mn = fmaxf(mrun[q2], tmax[q2]);
        sfac[q2] = exp2f((mrun[q2] - mn) * L2E);
        mrun[q2] = mn;
      }
#pragma unroll
      for (int q2 = 0; q2 < 2; ++q2)
#pragma unroll
        for (int e = 0; e < 4; ++e) {
          const float so = __shfl(sfac[q2], (lg << 2) + e);  // col -> row bcast
          oden[q2][e] *= so;
#pragma unroll
          for (int df = 0; df < 4; ++df) oac[q2][df][e] *= so;
        }
    }
    const float mL0 = mrun[0] * L2E, mL1 = mrun[1] * L2E;
#pragma unroll
    for (int kf = 0; kf < 4; ++kf)
#pragma unroll
      for (int q2 = 0; q2 < 2; ++q2) {
        const float mL = q2 ? mL1 : mL0;
        ushort4 pk;
        unsigned short* pp = &pk.x;
#pragma unroll
        for (int e = 0; e < 4; ++e)
          pp[e] = bf_bits(exp2f(fmaf(st[kf][q2][e], L2E, -mL)));
        *(ushort4*)(Plds + (q2 * 16 + l15) * 72 + kf * 16 + (lg << 2)) = pk;
      }
    // Issue V loads (vmcnt) so they fly under the lgkm fence + P reads.
    bf16x8v vreg[2][4];
#pragma unroll
    for (int x2 = 0; x2 < 2; ++x2)
#pragma unroll
      for (int df = 0; df < 4; ++df)
        vreg[x2][df] =
            *(const bf16x8v*)(v_p + (size_t)(df * 16 + l15) * 2048 + kb + x2 * 32 + lg * 8);
    // cross-lane (within-wave) LDS handoff fence: lgkmcnt(0) only.
    asm volatile("s_waitcnt lgkmcnt(0)" ::: "memory");
    __builtin_amdgcn_sched_barrier(0);
    bf16x8v pa[2][2];
#pragma unroll
    for (int x2 = 0; x2 < 2; ++x2)
#pragma unroll
      for (int q2 = 0; q2 < 2; ++q2)
        pa[x2][q2] = *(const bf16x8v*)(Plds + (q2 * 16 + l15) * 72 + x2 * 32 + lg * 8);
    asm volatile("" ::: "memory");
#pragma unroll
    for (int x2 = 0; x2 < 2; ++x2) {
#pragma unroll
      for (int q2 = 0; q2 < 2; ++q2)
        oden[q2] = MFMA_BF16(pa[x2][q2], ones8, oden[q2]);
#pragma unroll
      for (int df = 0; df < 4; ++df)
#pragma unroll
        for (int q2 = 0; q2 < 2; ++q2)
          oac[q2][df] = MFMA_BF16(pa[x2][q2], vreg[x2][df], oac[q2][df]);
    }
  }

  // ---- cross-wave merge: wave1 publishes partials, wave0 combines+writes ----
  __syncthreads();
  if (wv == 1) {
    float* dst = &Xch[lane][0];
    dst[0] = mrun[0];
    dst[1] = mrun[1];
#pragma unroll
    for (int q2 = 0; q2 < 2; ++q2)
#pragma unroll
      for (int e = 0; e < 4; ++e) dst[2 + q2 * 4 + e] = oden[q2][e];
#pragma unroll
    for (int q2 = 0; q2 < 2; ++q2)
#pragma unroll
      for (int df = 0; df < 4; ++df)
#pragma unroll
        for (int e = 0; e < 4; ++e)
          dst[10 + q2 * 16 + df * 4 + e] = oac[q2][df][e];
  }
  __syncthreads();
  if (wv == 0) {
    const float* src = &Xch[lane][0];
#pragma unroll
    for (int q2 = 0; q2 < 2; ++q2) {
      // COLUMN-indexed (per l15) merge factors...
      const float m1 = src[q2];
      const float mm = fmaxf(mrun[q2], m1);
      const float f0c = exp2f((mrun[q2] - mm) * L2E);
      const float f1c = exp2f((m1 - mm) * L2E);
#pragma unroll
      for (int e = 0; e < 4; ++e) {
        // ...broadcast to ROW positions (accumulator row = lg*4+e) before use.
        const float f0 = __shfl(f0c, (lg << 2) + e);
        const float f1 = __shfl(f1c, (lg << 2) + e);
        oden[q2][e] = oden[q2][e] * f0 + src[2 + q2 * 4 + e] * f1;
#pragma unroll
        for (int df = 0; df < 4; ++df)
          oac[q2][df][e] = oac[q2][df][e] * f0 + src[10 + q2 * 16 + df * 4 + e] * f1;
      }
    }
#pragma unroll
    for (int q2 = 0; q2 < 2; ++q2) {
      float li[4];
#pragma unroll
      for (int e = 0; e < 4; ++e) li[e] = 1.0f / oden[q2][e];
#pragma unroll
      for (int df = 0; df < 4; ++df)
#pragma unroll
        for (int e = 0; e < 4; ++e) {
          const int qr = qbase + q2 * 16 + (lg << 2) + e;
          const int dh = df * 16 + l15;
          Yp[(size_t)(b * 2048 + qr) * 1024 + h * 64 + dh] =
              __float2bfloat16(oac[q2][df][e] * li[e]);
        }
    }
  }
}

// ----------------------------------------------------------------- gemm_out --
// Y = Yp @ Wo^T, M=4096 N=1024 K=1024. 64x128 tiles -> 512 blocks (2/CU).
__global__ __launch_bounds__(256) void gemm_out(const bf16* __restrict__ A,
                                                const bf16* __restrict__ B,
                                                float* __restrict__ C) {
  const int K = 1024;
  const int NT = 8;
  __shared__ __attribute__((aligned(16))) bf16 As[2048], Bs[4096];
  const int t = threadIdx.x;
  const int lane = t & 63;
  const int wave = t >> 6;
  const int wr = wave >> 1, wc = wave & 1;
  int bid = blockIdx.x;
  bid = (bid & 7) * (512 >> 3) + (bid >> 3);
  const int bm = bid / NT, bn = bid % NT;
  const int brow = bm * 64, bcol = bn * 128;
  const bf16* pA = A + (size_t)brow * K;
  const bf16* pB = B + (size_t)bcol * K;
  const int r0 = t >> 2;
  const int c0 = (t & 3) * 8;
  f32x4 acc[2][4] = {};
  for (int k0 = 0; k0 < K; k0 += 32) {
    __syncthreads();
    GLD_LDS16(pA + (size_t)r0 * K + k0 + c0,        &As[t * 8]);
    GLD_LDS16(pB + (size_t)r0 * K + k0 + c0,        &Bs[t * 8]);
    GLD_LDS16(pB + (size_t)(r0 + 64) * K + k0 + c0, &Bs[2048 + t * 8]);
    __syncthreads();
    bf16x8v af[2], bf_[4];
    const int l15 = lane & 15, lg = lane >> 4;
#pragma unroll
    for (int i = 0; i < 2; ++i)
      af[i] = *(const bf16x8v*)&As[(wr * 32 + i * 16 + l15) * 32 + lg * 8];
#pragma unroll
    for (int j = 0; j < 4; ++j) {
      const int rB = wc * 64 + j * 16 + l15;
      bf_[j] = *(const bf16x8v*)&Bs[(rB & 63) * 32 + (rB >> 6) * 2048 + lg * 8];
    }
#pragma unroll
    for (int i = 0; i < 2; ++i)
#pragma unroll
      for (int j = 0; j < 4; ++j)
        acc[i][j] = MFMA_BF16(af[i], bf_[j], acc[i][j]);
  }
#pragma unroll
  for (int i = 0; i < 2; ++i)
#pragma unroll
    for (int j = 0; j < 4; ++j)
#pragma unroll
      for (int e = 0; e < 4; ++e) {
        const int m = brow + wr * 32 + i * 16 + ((lane >> 4) << 2) + e;
        const int n = bcol + wc * 64 + j * 16 + (lane & 15);
        C[(size_t)m * 1024 + n] = acc[i][j][e];
      }
}

// -------------------------------------------------------------------- launch --
extern "C" void kernel_launch(void* const* d_in, const int* in_sizes, int n_in,
                              void* d_out, int out_size, void* d_ws, size_t ws_size,
                              hipStream_t stream) {
  (void)in_sizes; (void)n_in; (void)out_size; (void)ws_size;
  const float* x    = (const float*)d_in[0];
  const float* wqkv = (const float*)d_in[1];
  const float* wo   = (const float*)d_in[2];
  float* out = (float*)d_out;

  const size_t NX = 4096ull * 1024;
  const size_t NW = 3072ull * 1024;
  const size_t NO = 1024ull * 1024;

  bf16* p = (bf16*)d_ws;
  bf16* xh  = p; p += NX;
  bf16* xl  = p; p += NX;
  bf16* wqh = p; p += NW;
  bf16* wql = p; p += NW;
  bf16* wob = p; p += NO;
  bf16* qhi = p; p += NX;
  bf16* qlo = p; p += NX;
  bf16* khi = p; p += NX;
  bf16* klo = p; p += NX;
  bf16* vt  = p; p += NX;
  bf16* yp  = p; p += NX;

  hipLaunchKernelGGL(cvt_split, dim3(NX / 1024), dim3(256), 0, stream, x, xh, xl, (int)NX);
  hipLaunchKernelGGL(cvt_split, dim3(NW / 1024), dim3(256), 0, stream, wqkv, wqh, wql, (int)NW);
  hipLaunchKernelGGL(cvt_plain, dim3(NO / 1024), dim3(256), 0, stream, wo, wob, (int)NO);
  hipLaunchKernelGGL(gemm_qkv, dim3(32 * 24), dim3(256), 0, stream,
                     xh, xl, wqh, wql, qhi, qlo, khi, klo, vt);
  hipLaunchKernelGGL(attn_kernel, dim3(2048), dim3(128), 0, stream,
                     qhi, qlo, khi, klo, vt, yp);
  hipLaunchKernelGGL(gemm_out, dim3(64 * 8), dim3(256), 0, stream, yp, wob, out);
}

// Round 11
// 305.831 us; speedup vs baseline: 1.2999x; 1.0237x over previous
//
#include <hip/hip_runtime.h>
#include <hip/hip_bf16.h>

// CustomMHA (B=2,S=2048,D=1024,H=16,dh=64) for MI355X / gfx950.
//
//  1) cvt_split:  x, W_qkv f32 -> (hi,lo) bf16 pairs; W_o -> bf16.
//  2) gemm_qkv :  T = X @ Wqkv^T, split-bf16 (3 MFMA); pure-V col tiles plain.
//     Single-buffered staging (32KB LDS -> 4 blocks/CU) + XOR chunk-swizzle:
//     row-major [128][32] tiles read at 64B row stride are an 8-way bank
//     conflict; pre-permuting the GLOBAL source chunk (t&3)^((t>>3)&3) with a
//     matching XOR on the ds_read chunk ((row>>1)&3) spreads 16 lanes over 8
//     banks -> 2-way = free. LDS stays linear (global_load_lds constraint).
//  3) attn      :  K-SPLIT 2-wave blocks, launch_bounds(128,2) (no spills).
//  4) gemm_out :  Y = Yp @ Wo^T, 64x128 tiles, same swizzle.

using bf16 = __hip_bfloat16;
typedef __attribute__((ext_vector_type(8))) short bf16x8v;   // 8 bf16 in 4 VGPRs
typedef __attribute__((ext_vector_type(4))) float f32x4;

#define MFMA_BF16(A, B, C) __builtin_amdgcn_mfma_f32_16x16x32_bf16((A), (B), (C), 0, 0, 0)

#define GLD_LDS16(g, l)                                                        \
  __builtin_amdgcn_global_load_lds(                                            \
      (const __attribute__((address_space(1))) void*)(g),                      \
      (__attribute__((address_space(3))) void*)(l), 16, 0, 0)

static __device__ __forceinline__ unsigned short bf_bits(float f) {
  bf16 b = __float2bfloat16(f);
  return *reinterpret_cast<unsigned short*>(&b);
}

// ---------------------------------------------------------------- converts --
__global__ __launch_bounds__(256) void cvt_split(const float* __restrict__ in,
                                                 bf16* __restrict__ hi,
                                                 bf16* __restrict__ lo, int n) {
  int i = (blockIdx.x * 256 + threadIdx.x) * 4;
  if (i >= n) return;
  const float4 v = *(const float4*)(in + i);
  float vv[4] = {v.x, v.y, v.z, v.w};
  ushort4 hb, lb;
  unsigned short* hp = &hb.x;
  unsigned short* lp = &lb.x;
#pragma unroll
  for (int j = 0; j < 4; ++j) {
    bf16 h = __float2bfloat16(vv[j]);
    float r = vv[j] - __bfloat162float(h);
    hp[j] = bf_bits(vv[j]);
    lp[j] = bf_bits(r);
  }
  *(ushort4*)(hi + i) = hb;
  *(ushort4*)(lo + i) = lb;
}

__global__ __launch_bounds__(256) void cvt_plain(const float* __restrict__ in,
                                                 bf16* __restrict__ out, int n) {
  int i = (blockIdx.x * 256 + threadIdx.x) * 4;
  if (i >= n) return;
  const float4 v = *(const float4*)(in + i);
  ushort4 ob;
  ob.x = bf_bits(v.x); ob.y = bf_bits(v.y); ob.z = bf_bits(v.z); ob.w = bf_bits(v.w);
  *(ushort4*)(out + i) = ob;
}

// ----------------------------------------------------------------- gemm_qkv --
// 128x128 tile, 256 thr (4 waves 2x2), BK=32, single-buffer + chunk swizzle.
__global__ __launch_bounds__(256) void gemm_qkv(
    const bf16* __restrict__ Ah, const bf16* __restrict__ Al,
    const bf16* __restrict__ Bh, const bf16* __restrict__ Bl,
    bf16* __restrict__ Qhi, bf16* __restrict__ Qlo,
    bf16* __restrict__ Khi, bf16* __restrict__ Klo,
    bf16* __restrict__ Vt) {
  const int K = 1024;
  const int NT = 24;  // 3072/128
  __shared__ __attribute__((aligned(16))) bf16 AsH[4096], AsL[4096], BsH[4096], BsL[4096];
  const int t = threadIdx.x;
  const int lane = t & 63;
  const int wave = t >> 6;
  const int wr = wave >> 1, wc = wave & 1;
  int bid = blockIdx.x;
  bid = (bid & 7) * (768 >> 3) + (bid >> 3);   // bijective XCD swizzle
  const int bm = bid / NT, bn = bid % NT;
  const int brow = bm * 128, bcol = bn * 128;
  const bool isV = (bcol >= 2048);
  const bf16* pAh = Ah + (size_t)brow * K;
  const bf16* pAl = Al + (size_t)brow * K;
  const bf16* pBh = Bh + (size_t)bcol * K;
  const bf16* pBl = Bl + (size_t)bcol * K;
  const int r0 = t >> 2;
  // swizzled source chunk: LDS[r][c'] holds global (r, c' ^ ((r>>1)&3))
  const int c0 = (((t & 3) ^ ((t >> 3) & 3))) * 8;
  f32x4 acc[4][4] = {};
  const int l15 = lane & 15;
  const int lg  = lane >> 4;
  // swizzled read chunk: elem = row*32 + (lg ^ ((row>>1)&3))*8; (row>>1)&3 ==
  // (l15>>1)&3 for all i (wr*64 and i*16 are 0 mod 8).
  const int cxor = (l15 >> 1) & 3;
  const int ao = (wr * 64 + l15) * 32 + ((lg ^ cxor)) * 8;
  const int bo = (wc * 64 + l15) * 32 + ((lg ^ cxor)) * 8;
  for (int k0 = 0; k0 < K; k0 += 32) {
    __syncthreads();
    GLD_LDS16(pAh + (size_t)r0 * K + k0 + c0,        &AsH[t * 8]);
    GLD_LDS16(pAh + (size_t)(r0 + 64) * K + k0 + c0, &AsH[2048 + t * 8]);
    GLD_LDS16(pBh + (size_t)r0 * K + k0 + c0,        &BsH[t * 8]);
    GLD_LDS16(pBh + (size_t)(r0 + 64) * K + k0 + c0, &BsH[2048 + t * 8]);
    if (!isV) {
      GLD_LDS16(pAl + (size_t)r0 * K + k0 + c0,        &AsL[t * 8]);
      GLD_LDS16(pAl + (size_t)(r0 + 64) * K + k0 + c0, &AsL[2048 + t * 8]);
      GLD_LDS16(pBl + (size_t)r0 * K + k0 + c0,        &BsL[t * 8]);
      GLD_LDS16(pBl + (size_t)(r0 + 64) * K + k0 + c0, &BsL[2048 + t * 8]);
    }
    __syncthreads();
    bf16x8v ah[4], bh_[4];
#pragma unroll
    for (int i = 0; i < 4; ++i) {
      ah[i]  = *(const bf16x8v*)&AsH[ao + i * 512];
      bh_[i] = *(const bf16x8v*)&BsH[bo + i * 512];
    }
    if (!isV) {
      bf16x8v al[4], bl_[4];
#pragma unroll
      for (int i = 0; i < 4; ++i) {
        al[i]  = *(const bf16x8v*)&AsL[ao + i * 512];
        bl_[i] = *(const bf16x8v*)&BsL[bo + i * 512];
      }
#pragma unroll
      for (int i = 0; i < 4; ++i)
#pragma unroll
        for (int j = 0; j < 4; ++j) {
          acc[i][j] = MFMA_BF16(ah[i], bh_[j], acc[i][j]);
          acc[i][j] = MFMA_BF16(ah[i], bl_[j], acc[i][j]);
          acc[i][j] = MFMA_BF16(al[i], bh_[j], acc[i][j]);
        }
    } else {
#pragma unroll
      for (int i = 0; i < 4; ++i)
#pragma unroll
        for (int j = 0; j < 4; ++j)
          acc[i][j] = MFMA_BF16(ah[i], bh_[j], acc[i][j]);
    }
  }
  // epilogue: split + scatter (V transposed); Q pre-scaled by 1/32.
#pragma unroll
  for (int i = 0; i < 4; ++i)
#pragma unroll
    for (int j = 0; j < 4; ++j)
#pragma unroll
      for (int e = 0; e < 4; ++e) {
        const int m = brow + wr * 64 + i * 16 + ((lane >> 4) << 2) + e;
        const int n = bcol + wc * 64 + j * 16 + (lane & 15);
        float v = acc[i][j][e];
        const int b = m >> 11, s = m & 2047;
        const int c = n >> 10, d = n & 1023;
        const int bh_i = (b << 4) | (s >> 7);
        const int s2 = ((s & 127) << 4) | (d >> 6);
        const int dh = d & 63;
        if (c == 2) {
          Vt[((size_t)bh_i << 17) | ((size_t)dh << 11) | (size_t)s2] = __float2bfloat16(v);
        } else {
          if (c == 0) v *= 0.03125f;
          const size_t idx = ((size_t)bh_i << 17) | ((size_t)s2 << 6) | (size_t)dh;
          bf16 hv = __float2bfloat16(v);
          bf16 lv = __float2bfloat16(v - __bfloat162float(hv));
          if (c == 0) { Qhi[idx] = hv; Qlo[idx] = lv; }
          else        { Khi[idx] = hv; Klo[idx] = lv; }
        }
      }
}

// --------------------------------------------------------------------- attn --
// 2048 blocks x 128 thr: 2 waves split the k-tiles of one (bh, 32-row chunk).
// launch_bounds(128,2): VGPR cap >=128 so the ~125 live regs do NOT spill.
__global__ __launch_bounds__(128, 2) void attn_kernel(
    const bf16* __restrict__ Qhi, const bf16* __restrict__ Qlo,
    const bf16* __restrict__ Khi, const bf16* __restrict__ Klo,
    const bf16* __restrict__ Vt, bf16* __restrict__ Yp) {
  const int lane = threadIdx.x & 63;
  const int wv   = threadIdx.x >> 6;       // k-split half (0 or 1)
  const int bh = blockIdx.x & 31;          // bh minor (bh%8 pins the XCD)
  const int c  = 63 - (blockIdx.x >> 5);   // chunk, longest first
  const int b = bh >> 4, h = bh & 15;
  const size_t base = (size_t)bh << 17;
  const bf16* qh_p = Qhi + base;
  const bf16* ql_p = Qlo + base;
  const bf16* kh_p = Khi + base;
  const bf16* kl_p = Klo + base;
  const bf16* v_p  = Vt + base;            // (dh, s2) layout
  const int qbase = c << 5;
  const int l15 = lane & 15;
  const int lg  = lane >> 4;

  __shared__ __attribute__((aligned(16))) float Xch[64][44];
  bf16* Plds = reinterpret_cast<bf16*>(&Xch[0][0]) + wv * 2304;  // [32][72]

  bf16x8v qfh[2][2], qfl[2][2];
#pragma unroll
  for (int q2 = 0; q2 < 2; ++q2)
#pragma unroll
    for (int x2 = 0; x2 < 2; ++x2) {
      const size_t o = (size_t)(qbase + q2 * 16 + l15) * 64 + x2 * 32 + lg * 8;
      qfh[q2][x2] = *(const bf16x8v*)(qh_p + o);
      qfl[q2][x2] = *(const bf16x8v*)(ql_p + o);
    }
  bf16x8v ones8;
#pragma unroll
  for (int j = 0; j < 8; ++j) ones8[j] = (short)0x3F80;

  f32x4 oac[2][4] = {};
  f32x4 oden[2] = {};
  float mrun[2] = {-3.0e38f, -3.0e38f};
  const float L2E = 1.4426950408889634f;
  const int n  = (c >> 1) + 1;             // total k-tiles for this chunk
  const int h0 = (n + 1) >> 1;             // wave0: [0,h0)  wave1: [h0,n)
  const int kt0 = wv ? h0 : 0;
  const int kt1 = wv ? n : h0;
  const int diag = n - 1;

  for (int kt = kt0; kt < kt1; ++kt) {
    const int kb = kt << 6;
    f32x4 st[4][2] = {};
#pragma unroll
    for (int kf = 0; kf < 4; ++kf) {
      const size_t ko = (size_t)(kb + kf * 16 + l15) * 64 + lg * 8;
      const bf16x8v kh0 = *(const bf16x8v*)(kh_p + ko);
      const bf16x8v kh1 = *(const bf16x8v*)(kh_p + ko + 32);
      const bf16x8v kl0 = *(const bf16x8v*)(kl_p + ko);
      const bf16x8v kl1 = *(const bf16x8v*)(kl_p + ko + 32);
#pragma unroll
      for (int q2 = 0; q2 < 2; ++q2) {
        f32x4 a = st[kf][q2];
        a = MFMA_BF16(kh0, qfh[q2][0], a);
        a = MFMA_BF16(kh1, qfh[q2][1], a);
        a = MFMA_BF16(kh0, qfl[q2][0], a);
        a = MFMA_BF16(kh1, qfl[q2][1], a);
        a = MFMA_BF16(kl0, qfh[q2][0], a);
        a = MFMA_BF16(kl1, qfh[q2][1], a);
        st[kf][q2] = a;
      }
    }
    if (kt == diag) {                      // causal mask, diagonal tile only
#pragma unroll
      for (int kf = 0; kf < 4; ++kf)
#pragma unroll
        for (int q2 = 0; q2 < 2; ++q2)
#pragma unroll
          for (int e = 0; e < 4; ++e) {
            const int key = kb + kf * 16 + (lg << 2) + e;
            const int qr  = qbase + q2 * 16 + l15;
            if (key > qr) st[kf][q2][e] = -3.0e38f;
          }
    }
    float tmax[2] = {-3.0e38f, -3.0e38f};
#pragma unroll
    for (int kf = 0; kf < 4; ++kf)
#pragma unroll
      for (int q2 = 0; q2 < 2; ++q2)
#pragma unroll
        for (int e = 0; e < 4; ++e)
          tmax[q2] = fmaxf(tmax[q2], st[kf][q2][e]);
#pragma unroll
    for (int q2 = 0; q2 < 2; ++q2) {
      tmax[q2] = fmaxf(tmax[q2], __shfl_xor(tmax[q2], 16));
      tmax[q2] = fmaxf(tmax[q2], __shfl_xor(tmax[q2], 32));
    }
    const int ok = (tmax[0] <= mrun[0] + 8.0f) && (tmax[1] <= mrun[1] + 8.0f);
    if (!__all(ok)) {
      float sfac[2];
#pragma unroll
      for (int q2 = 0; q2 < 2; ++q2) {
        const float mn = fmaxf(mrun[q2], tmax[q2]);
        sfac[q2] = exp2f((mrun[q2] - mn) * L2E);
        mrun[q2] = mn;
      }
#pragma unroll
      for (int q2 = 0; q2 < 2; ++q2)
#pragma unroll
        for (int e = 0; e < 4; ++e) {
          const float so = __shfl(sfac[q2], (lg << 2) + e);  // col -> row bcast
          oden[q2][e] *= so;
#pragma unroll
          for (int df = 0; df < 4; ++df) oac[q2][df][e] *= so;
        }
    }
    const float mL0 = mrun[0] * L2E, mL1 = mrun[1] * L2E;
#pragma unroll
    for (int kf = 0; kf < 4; ++kf)
#pragma unroll
      for (int q2 = 0; q2 < 2; ++q2) {
        const float mL = q2 ? mL1 : mL0;
        ushort4 pk;
        unsigned short* pp = &pk.x;
#pragma unroll
        for (int e = 0; e < 4; ++e)
          pp[e] = bf_bits(exp2f(fmaf(st[kf][q2][e], L2E, -mL)));
        *(ushort4*)(Plds + (q2 * 16 + l15) * 72 + kf * 16 + (lg << 2)) = pk;
      }
    bf16x8v vreg[2][4];
#pragma unroll
    for (int x2 = 0; x2 < 2; ++x2)
#pragma unroll
      for (int df = 0; df < 4; ++df)
        vreg[x2][df] =
            *(const bf16x8v*)(v_p + (size_t)(df * 16 + l15) * 2048 + kb + x2 * 32 + lg * 8);
    asm volatile("s_waitcnt lgkmcnt(0)" ::: "memory");
    __builtin_amdgcn_sched_barrier(0);
    bf16x8v pa[2][2];
#pragma unroll
    for (int x2 = 0; x2 < 2; ++x2)
#pragma unroll
      for (int q2 = 0; q2 < 2; ++q2)
        pa[x2][q2] = *(const bf16x8v*)(Plds + (q2 * 16 + l15) * 72 + x2 * 32 + lg * 8);
    asm volatile("" ::: "memory");
#pragma unroll
    for (int x2 = 0; x2 < 2; ++x2) {
#pragma unroll
      for (int q2 = 0; q2 < 2; ++q2)
        oden[q2] = MFMA_BF16(pa[x2][q2], ones8, oden[q2]);
#pragma unroll
      for (int df = 0; df < 4; ++df)
#pragma unroll
        for (int q2 = 0; q2 < 2; ++q2)
          oac[q2][df] = MFMA_BF16(pa[x2][q2], vreg[x2][df], oac[q2][df]);
    }
  }

  // ---- cross-wave merge: wave1 publishes partials, wave0 combines+writes ----
  __syncthreads();
  if (wv == 1) {
    float* dst = &Xch[lane][0];
    dst[0] = mrun[0];
    dst[1] = mrun[1];
#pragma unroll
    for (int q2 = 0; q2 < 2; ++q2)
#pragma unroll
      for (int e = 0; e < 4; ++e) dst[2 + q2 * 4 + e] = oden[q2][e];
#pragma unroll
    for (int q2 = 0; q2 < 2; ++q2)
#pragma unroll
      for (int df = 0; df < 4; ++df)
#pragma unroll
        for (int e = 0; e < 4; ++e)
          dst[10 + q2 * 16 + df * 4 + e] = oac[q2][df][e];
  }
  __syncthreads();
  if (wv == 0) {
    const float* src = &Xch[lane][0];
#pragma unroll
    for (int q2 = 0; q2 < 2; ++q2) {
      const float m1 = src[q2];
      const float mm = fmaxf(mrun[q2], m1);
      const float f0c = exp2f((mrun[q2] - mm) * L2E);
      const float f1c = exp2f((m1 - mm) * L2E);
#pragma unroll
      for (int e = 0; e < 4; ++e) {
        const float f0 = __shfl(f0c, (lg << 2) + e);
        const float f1 = __shfl(f1c, (lg << 2) + e);
        oden[q2][e] = oden[q2][e] * f0 + src[2 + q2 * 4 + e] * f1;
#pragma unroll
        for (int df = 0; df < 4; ++df)
          oac[q2][df][e] = oac[q2][df][e] * f0 + src[10 + q2 * 16 + df * 4 + e] * f1;
      }
    }
#pragma unroll
    for (int q2 = 0; q2 < 2; ++q2) {
      float li[4];
#pragma unroll
      for (int e = 0; e < 4; ++e) li[e] = 1.0f / oden[q2][e];
#pragma unroll
      for (int df = 0; df < 4; ++df)
#pragma unroll
        for (int e = 0; e < 4; ++e) {
          const int qr = qbase + q2 * 16 + (lg << 2) + e;
          const int dh = df * 16 + l15;
          Yp[(size_t)(b * 2048 + qr) * 1024 + h * 64 + dh] =
              __float2bfloat16(oac[q2][df][e] * li[e]);
        }
    }
  }
}

// ----------------------------------------------------------------- gemm_out --
// Y = Yp @ Wo^T, M=4096 N=1024 K=1024. 64x128 tiles, chunk swizzle.
__global__ __launch_bounds__(256) void gemm_out(const bf16* __restrict__ A,
                                                const bf16* __restrict__ B,
                                                float* __restrict__ C) {
  const int K = 1024;
  const int NT = 8;
  __shared__ __attribute__((aligned(16))) bf16 As[2048], Bs[4096];
  const int t = threadIdx.x;
  const int lane = t & 63;
  const int wave = t >> 6;
  const int wr = wave >> 1, wc = wave & 1;
  int bid = blockIdx.x;
  bid = (bid & 7) * (512 >> 3) + (bid >> 3);
  const int bm = bid / NT, bn = bid % NT;
  const int brow = bm * 64, bcol = bn * 128;
  const bf16* pA = A + (size_t)brow * K;
  const bf16* pB = B + (size_t)bcol * K;
  const int r0 = t >> 2;
  const int c0 = (((t & 3) ^ ((t >> 3) & 3))) * 8;   // swizzled source chunk
  const int l15 = lane & 15, lg = lane >> 4;
  const int cxor = (l15 >> 1) & 3;
  f32x4 acc[2][4] = {};
  for (int k0 = 0; k0 < K; k0 += 32) {
    __syncthreads();
    GLD_LDS16(pA + (size_t)r0 * K + k0 + c0,        &As[t * 8]);
    GLD_LDS16(pB + (size_t)r0 * K + k0 + c0,        &Bs[t * 8]);
    GLD_LDS16(pB + (size_t)(r0 + 64) * K + k0 + c0, &Bs[2048 + t * 8]);
    __syncthreads();
    bf16x8v af[2], bf_[4];
#pragma unroll
    for (int i = 0; i < 2; ++i)
      af[i] = *(const bf16x8v*)&As[(wr * 32 + i * 16 + l15) * 32 + (lg ^ cxor) * 8];
#pragma unroll
    for (int j = 0; j < 4; ++j) {
      const int rB = wc * 64 + j * 16 + l15;
      bf_[j] = *(const bf16x8v*)&Bs[(rB & 63) * 32 + (rB >> 6) * 2048 + (lg ^ cxor) * 8];
    }
#pragma unroll
    for (int i = 0; i < 2; ++i)
#pragma unroll
      for (int j = 0; j < 4; ++j)
        acc[i][j] = MFMA_BF16(af[i], bf_[j], acc[i][j]);
  }
#pragma unroll
  for (int i = 0; i < 2; ++i)
#pragma unroll
    for (int j = 0; j < 4; ++j)
#pragma unroll
      for (int e = 0; e < 4; ++e) {
        const int m = brow + wr * 32 + i * 16 + ((lane >> 4) << 2) + e;
        const int n = bcol + wc * 64 + j * 16 + (lane & 15);
        C[(size_t)m * 1024 + n] = acc[i][j][e];
      }
}

// -------------------------------------------------------------------- launch --
extern "C" void kernel_launch(void* const* d_in, const int* in_sizes, int n_in,
                              void* d_out, int out_size, void* d_ws, size_t ws_size,
                              hipStream_t stream) {
  (void)in_sizes; (void)n_in; (void)out_size; (void)ws_size;
  const float* x    = (const float*)d_in[0];
  const float* wqkv = (const float*)d_in[1];
  const float* wo   = (const float*)d_in[2];
  float* out = (float*)d_out;

  const size_t NX = 4096ull * 1024;
  const size_t NW = 3072ull * 1024;
  const size_t NO = 1024ull * 1024;

  bf16* p = (bf16*)d_ws;
  bf16* xh  = p; p += NX;
  bf16* xl  = p; p += NX;
  bf16* wqh = p; p += NW;
  bf16* wql = p; p += NW;
  bf16* wob = p; p += NO;
  bf16* qhi = p; p += NX;
  bf16* qlo = p; p += NX;
  bf16* khi = p; p += NX;
  bf16* klo = p; p += NX;
  bf16* vt  = p; p += NX;
  bf16* yp  = p; p += NX;

  hipLaunchKernelGGL(cvt_split, dim3(NX / 1024), dim3(256), 0, stream, x, xh, xl, (int)NX);
  hipLaunchKernelGGL(cvt_split, dim3(NW / 1024), dim3(256), 0, stream, wqkv, wqh, wql, (int)NW);
  hipLaunchKernelGGL(cvt_plain, dim3(NO / 1024), dim3(256), 0, stream, wo, wob, (int)NO);
  hipLaunchKernelGGL(gemm_qkv, dim3(32 * 24), dim3(256), 0, stream,
                     xh, xl, wqh, wql, qhi, qlo, khi, klo, vt);
  hipLaunchKernelGGL(attn_kernel, dim3(2048), dim3(128), 0, stream,
                     qhi, qlo, khi, klo, vt, yp);
  hipLaunchKernelGGL(gemm_out, dim3(64 * 8), dim3(256), 0, stream, yp, wob, out);
}